// Round 2
// baseline (231.453 us; speedup 1.0000x reference)
//
#include <hip/hip_runtime.h>

// out[b,o,h,w] = sum_i x[b,i,h,w] * Khat[o,i,h,w]         (complex, x real)
// Khat[i,o](h,w) = sum_p e_h[p] * G[w][p][o][i],  G = sum_q W[o,i,p,q] e_w[q]
// e_h[p] = exp(-2*pi*i*h*p/256), e_w[q] = exp(-2*pi*i*w*q/256)
// Output: (2, B, COUT, H, W) fp32.

typedef _Float16 half4 __attribute__((ext_vector_type(4)));
typedef float floatx4 __attribute__((ext_vector_type(4)));

constexpr int Hd = 256, Wd = 256;
constexpr int TW = 16;                  // w-tile per block
constexpr float TWO_PI = 6.283185307179586f;

// ---------------- kernel 1: G[w][p][o][i] complex, 1.57 MB ----------------
__global__ __launch_bounds__(256)
void build_G(const float* __restrict__ wr, const float* __restrict__ wi,
             float* __restrict__ G) {
    const int w = blockIdx.x;           // 256
    const int t = threadIdx.x;          // 256 = (o,i)
    const int o = t >> 4, i = t & 15;
    float s1, c1;
    __sincosf((TWO_PI / 256.f) * (float)w, &s1, &c1);
    const float ewr[3] = {1.f, c1, c1 * c1 - s1 * s1};
    const float ewi[3] = {0.f, -s1, -2.f * s1 * c1};
    const float* a = &wr[(o * 16 + i) * 9];
    const float* b = &wi[(o * 16 + i) * 9];
#pragma unroll
    for (int p = 0; p < 3; ++p) {
        float gr = 0.f, gi = 0.f;
#pragma unroll
        for (int q = 0; q < 3; ++q) {
            const float A = a[p * 3 + q], B = b[p * 3 + q];
            gr += A * ewr[q] - B * ewi[q];
            gi += A * ewi[q] + B * ewr[q];
        }
        reinterpret_cast<float2*>(G)[(w * 3 + p) * 256 + o * 16 + i] =
            make_float2(gr, gi);
    }
}

// ---------------- kernel 2: per-pixel MFMA contraction ----------------
__global__ __launch_bounds__(512)
void freq_conv_mfma(const float* __restrict__ x, const float* __restrict__ G,
                    float* __restrict__ out) {
    __shared__ float XS[TW * 256];      // [w][rot(b*16+i)] f32, 16 KB
    __shared__ float CB[2 * 256 * 20];  // [part][b*16+o][16w + pad4], 40 KB

    const int tid  = threadIdx.x;
    const int bid  = blockIdx.x;        // 4096 = 256 h * 16 w-tiles
    const int h    = bid >> 4;
    const int w0   = (bid & 15) * TW;
    const int lane = tid & 63;
    const int wave = tid >> 6;          // 0..7
    const int nlo  = lane & 15;         // b for A / o for B,C
    const int hi   = lane >> 4;         // k-group

    // ---- stage X[b,i, w0..w0+15] -> XS[w][(r + 4*(w>>2)) & 255] ----
#pragma unroll
    for (int k = 0; k < 2; ++k) {
        const int idx = k * 512 + tid;  // 0..1023 float4 chunks
        const int r   = idx >> 2;       // row b*16+i, 0..255
        const int c   = idx & 3;        // w-chunk of 4
        const float4 v = *reinterpret_cast<const float4*>(
            &x[(size_t)r * (Hd * Wd) + h * Wd + w0 + 4 * c]);
        const int rr = (r + 4 * c) & 255;   // rotate by floor(w/4)*4
        XS[(4 * c + 0) * 256 + rr] = v.x;
        XS[(4 * c + 1) * 256 + rr] = v.y;
        XS[(4 * c + 2) * 256 + rr] = v.z;
        XS[(4 * c + 3) * 256 + rr] = v.w;
    }

    float s1, c1;
    __sincosf((TWO_PI / 256.f) * (float)h, &s1, &c1);
    const float ehr[3] = {1.f, c1, c1 * c1 - s1 * s1};
    const float ehi[3] = {0.f, -s1, -2.f * s1 * c1};

    __syncthreads();

    // ---- 2 pixels per wave ----
#pragma unroll
    for (int kk = 0; kk < 2; ++kk) {
        const int wl = kk * 8 + wave;   // local w 0..15
        const int w  = w0 + wl;

        // A fragment: X[b][4*hi .. +3] (f32 -> f16)
        const float4 xa = *reinterpret_cast<const float4*>(
            &XS[wl * 256 + (((nlo * 16 + 4 * hi) + 4 * (wl >> 2)) & 255)]);
        const half4 Af = {(_Float16)xa.x, (_Float16)xa.y,
                          (_Float16)xa.z, (_Float16)xa.w};

        // B fragments: Khat[i = 4*hi+j][o = nlo], j = 0..3
        float Kr[4] = {0.f, 0.f, 0.f, 0.f}, Ki[4] = {0.f, 0.f, 0.f, 0.f};
#pragma unroll
        for (int p = 0; p < 3; ++p) {
            const float* gp = &G[((w * 3 + p) * 256 + nlo * 16 + 4 * hi) * 2];
            const float4 g0 = *reinterpret_cast<const float4*>(gp);
            const float4 g1 = *reinterpret_cast<const float4*>(gp + 4);
            const float er = ehr[p], ei = ehi[p];
            Kr[0] += er * g0.x - ei * g0.y;  Ki[0] += er * g0.y + ei * g0.x;
            Kr[1] += er * g0.z - ei * g0.w;  Ki[1] += er * g0.w + ei * g0.z;
            Kr[2] += er * g1.x - ei * g1.y;  Ki[2] += er * g1.y + ei * g1.x;
            Kr[3] += er * g1.z - ei * g1.w;  Ki[3] += er * g1.w + ei * g1.z;
        }
        const half4 Br = {(_Float16)Kr[0], (_Float16)Kr[1],
                          (_Float16)Kr[2], (_Float16)Kr[3]};
        const half4 Bi = {(_Float16)Ki[0], (_Float16)Ki[1],
                          (_Float16)Ki[2], (_Float16)Ki[3]};

        const floatx4 zero = {0.f, 0.f, 0.f, 0.f};
        const floatx4 Cr = __builtin_amdgcn_mfma_f32_16x16x16f16(Af, Br, zero, 0, 0, 0);
        const floatx4 Ci = __builtin_amdgcn_mfma_f32_16x16x16f16(Af, Bi, zero, 0, 0, 0);

        // C[b = 4*hi+r][o = nlo] -> CB[part][b*16+o][swizzled w]
        const int wsz = (wl + 4 * hi) & 15;
#pragma unroll
        for (int r = 0; r < 4; ++r) {
            const int row = (4 * hi + r) * 16 + nlo;
            CB[row * 20 + wsz]             = Cr[r];
            CB[256 * 20 + row * 20 + wsz]  = Ci[r];
        }
    }
    __syncthreads();

    // ---- coalesced flush: 512 rows x 16 w ----
#pragma unroll
    for (int pass = 0; pass < 4; ++pass) {
        const int R  = pass * 128 + (tid >> 2);   // 0..511 = part*256 + b*16 + o
        const int wp = tid & 3;
        const int b  = (R >> 4) & 15;
        const int wl_l = (4 * wp + 4 * (b >> 2)) & 15;  // un-swizzle
        const float4 v = *reinterpret_cast<const float4*>(
            &CB[(R >> 8) * (256 * 20) + (R & 255) * 20 + wl_l]);
        *reinterpret_cast<float4*>(
            &out[(size_t)R * (Hd * Wd) + h * Wd + w0 + 4 * wp]) = v;
    }
}

extern "C" void kernel_launch(void* const* d_in, const int* in_sizes, int n_in,
                              void* d_out, int out_size, void* d_ws, size_t ws_size,
                              hipStream_t stream) {
    const float* x  = (const float*)d_in[0];
    const float* wr = (const float*)d_in[1];
    const float* wi = (const float*)d_in[2];
    float* out = (float*)d_out;
    float* G   = (float*)d_ws;   // 256*3*256*2 floats = 1.57 MB

    build_G<<<256, 256, 0, stream>>>(wr, wi, G);
    freq_conv_mfma<<<Hd * (Wd / TW), 512, 0, stream>>>(x, G, out);
}

// Round 4
// 207.734 us; speedup vs baseline: 1.1142x; 1.1142x over previous
//
#include <hip/hip_runtime.h>

// out[b,o,h,w] = sum_i x[b,i,h,w] * Khat[o,i,h,w]        (complex, x real)
// Khat[i,o](h,w) = sum_p e_h[p] * G[w][p][o][i],  G = sum_q W[o,i,p,q] e_w[q]
// e_h[p] = (c_p, -s_p) = exp(-2*pi*i*h*p/256), likewise e_w.
// Output: (2, B, COUT, H, W) fp32; imag plane offset = B*COUT*H*W = 16777216.

typedef _Float16 half2v __attribute__((ext_vector_type(2)));
typedef _Float16 half4  __attribute__((ext_vector_type(4)));
typedef float   floatx4 __attribute__((ext_vector_type(4)));

constexpr int Hd = 256, Wd = 256;
constexpr int TW = 16;      // w-positions per block
constexpr int TH = 16;      // h-rows per block
constexpr int NT = 1024;    // 16 waves
constexpr int XSS = 280;    // f16 stride per w-row of XS
constexpr float TWO_PI = 6.283185307179586f;
constexpr size_t IMAG_OFF = (size_t)16 * 16 * Hd * Wd;   // 16,777,216 elements

__global__ __launch_bounds__(NT)
void freq_conv(const float* __restrict__ x,
               const float* __restrict__ wr_g,
               const float* __restrict__ wi_g,
               float* __restrict__ out)
{
    __shared__ __align__(16) unsigned int Gs[TW * 3 * 256];  // 48 KB packed (f16 re, f16 im)
    __shared__ __align__(16) _Float16 XS[2][TW * XSS];       // 2 x 8.75 KB, [w][b*16+i]
    __shared__ __align__(16) float CB[2 * 256 * 20];         // 40 KB transpose buf (also W staging)

    const int tid  = threadIdx.x;
    const int lane = tid & 63;
    const int wave = tid >> 6;          // 0..15 == local w (one pixel per wave per h)
    const int nlo  = lane & 15;
    const int hi   = lane >> 4;

    const int bid = blockIdx.x;         // 256 = 16 hgroups * 16 wtiles
    const int h0  = (bid >> 4) * TH;
    const int w0  = (bid & 15) * TW;

    // ---------- prologue ----------
    // issue x row h0 (each thread: one float4 of one (b,i) row)
    const int xrow = tid >> 2;          // 0..255 = b*16+i
    const int xwg  = tid & 3;           // float4 index within 16-w tile
    float4 xr = *reinterpret_cast<const float4*>(
        &x[(size_t)xrow * (Hd * Wd) + (size_t)h0 * Wd + w0 + 4 * xwg]);

    // stage W (wr:2304 f32, wi:2304 f32) into CB
    {
        float* WS = CB;
        if (tid < 576) {
            reinterpret_cast<float4*>(WS)[tid] =
                reinterpret_cast<const float4*>(wr_g)[tid];
        } else {
            reinterpret_cast<float4*>(WS + 2304)[tid - 576] =
                reinterpret_cast<const float4*>(wi_g)[tid - 576];
        }
        if (tid < 128) {
            reinterpret_cast<float4*>(WS + 2304)[448 + tid] =
                reinterpret_cast<const float4*>(wi_g)[448 + tid];
        }
    }
    __syncthreads();

    // build Gs[w][p][o*16+i] from W (in LDS): each thread -> oi fixed, 4 w's x 3 p
    {
        const float* Wr = CB;
        const float* Wi = CB + 2304;
        const int oi = tid & 255;
        const int g  = tid >> 8;        // 0..3
        float a[9], b9[9];
#pragma unroll
        for (int t = 0; t < 9; ++t) { a[t] = Wr[oi * 9 + t]; b9[t] = Wi[oi * 9 + t]; }
#pragma unroll
        for (int k = 0; k < 4; ++k) {
            const int wl = g + 4 * k;
            float s1, c1;
            __sincosf((TWO_PI / 256.f) * (float)(w0 + wl), &s1, &c1);
            const float cw[3] = {1.f, c1, c1 * c1 - s1 * s1};
            const float sw[3] = {0.f, s1, 2.f * s1 * c1};
#pragma unroll
            for (int p = 0; p < 3; ++p) {
                float gr = 0.f, gi = 0.f;
#pragma unroll
                for (int q = 0; q < 3; ++q) {
                    gr += a[p * 3 + q] * cw[q] + b9[p * 3 + q] * sw[q];
                    gi += b9[p * 3 + q] * cw[q] - a[p * 3 + q] * sw[q];
                }
                half2v hv = {(_Float16)gr, (_Float16)gi};
                Gs[(wl * 3 + p) * 256 + oi] = __builtin_bit_cast(unsigned int, hv);
            }
        }
    }

    // XS[0] <- row h0 (f16 transpose: [w][b*16+i]); then issue row h0+1
    {
#pragma unroll
        for (int j = 0; j < 4; ++j)
            XS[0][(4 * xwg + j) * XSS + xrow] = (_Float16)((&xr.x)[j]);
    }
    xr = *reinterpret_cast<const float4*>(
        &x[(size_t)xrow * (Hd * Wd) + (size_t)(h0 + 1) * Wd + w0 + 4 * xwg]);

    // ---------- main loop over h ----------
    for (int ih = 0; ih < TH; ++ih) {
        const int h = h0 + ih;
        __syncthreads();    // XS[ih&1] ready; CB free; Gs ready

        // stage next row into XS[nxt], issue load for h+2 (1-row pipeline)
        if (ih + 1 < TH) {
#pragma unroll
            for (int j = 0; j < 4; ++j)
                XS[(ih + 1) & 1][(4 * xwg + j) * XSS + xrow] = (_Float16)((&xr.x)[j]);
            if (ih + 2 < TH)
                xr = *reinterpret_cast<const float4*>(
                    &x[(size_t)xrow * (Hd * Wd) + (size_t)(h + 2) * Wd + w0 + 4 * xwg]);
        }

        // e_h phases (f32)
        float s1, c1;
        __sincosf((TWO_PI / 256.f) * (float)h, &s1, &c1);
        const float chv[3] = {1.f, c1, c1 * c1 - s1 * s1};
        const float shv[3] = {0.f, s1, 2.f * s1 * c1};

        // one pixel per wave: Khat build (f32 accumulation) + 2 MFMA
        const int wl = wave;
        float Kr[4] = {0.f, 0.f, 0.f, 0.f}, Ki[4] = {0.f, 0.f, 0.f, 0.f};
#pragma unroll
        for (int p = 0; p < 3; ++p) {
            const uint4 g4 = *reinterpret_cast<const uint4*>(
                &Gs[(wl * 3 + p) * 256 + nlo * 16 + 4 * hi]);
            const float er = chv[p], ei = shv[p];
            const unsigned int gw[4] = {g4.x, g4.y, g4.z, g4.w};
#pragma unroll
            for (int j = 0; j < 4; ++j) {
                const half2v gv = __builtin_bit_cast(half2v, gw[j]);
                const float gr = (float)gv.x, gi = (float)gv.y;
                // e^{-i th} * (gr + i gi): re = c*gr + s*gi, im = c*gi - s*gr
                Kr[j] += er * gr + ei * gi;
                Ki[j] += er * gi - ei * gr;
            }
        }
        const half4 Br = {(_Float16)Kr[0], (_Float16)Kr[1],
                          (_Float16)Kr[2], (_Float16)Kr[3]};
        const half4 Bi = {(_Float16)Ki[0], (_Float16)Ki[1],
                          (_Float16)Ki[2], (_Float16)Ki[3]};
        const half4 Af = *reinterpret_cast<const half4*>(
            &XS[ih & 1][wl * XSS + nlo * 16 + 4 * hi]);

        const floatx4 zero = {0.f, 0.f, 0.f, 0.f};
        const floatx4 Cr = __builtin_amdgcn_mfma_f32_16x16x16f16(Af, Br, zero, 0, 0, 0);
        const floatx4 Ci = __builtin_amdgcn_mfma_f32_16x16x16f16(Af, Bi, zero, 0, 0, 0);
#pragma unroll
        for (int r = 0; r < 4; ++r) {
            const int row = (4 * hi + r) * 16 + nlo;   // b*16 + o
            CB[row * 20 + wl]         = Cr[r];
            CB[(256 + row) * 20 + wl] = Ci[r];
        }

        __syncthreads();

        // flush CB -> out (coalesced float4 along w)
        {
            const int row4 = tid >> 2;   // 0..255 = b*16+o
            const int wp   = tid & 3;
            const float4 v0 = *reinterpret_cast<const float4*>(&CB[row4 * 20 + 4 * wp]);
            const float4 v1 = *reinterpret_cast<const float4*>(&CB[(256 + row4) * 20 + 4 * wp]);
            float* o0 = &out[(size_t)row4 * (Hd * Wd) + (size_t)h * Wd + w0 + 4 * wp];
            *reinterpret_cast<float4*>(o0) = v0;
            *reinterpret_cast<float4*>(o0 + IMAG_OFF) = v1;   // imag plane
        }
    }
}

extern "C" void kernel_launch(void* const* d_in, const int* in_sizes, int n_in,
                              void* d_out, int out_size, void* d_ws, size_t ws_size,
                              hipStream_t stream) {
    const float* x  = (const float*)d_in[0];
    const float* wr = (const float*)d_in[1];
    const float* wi = (const float*)d_in[2];
    float* out = (float*)d_out;

    freq_conv<<<dim3(256), dim3(NT), 0, stream>>>(x, wr, wi, out);
}